// Round 1
// baseline (402.654 us; speedup 1.0000x reference)
//
#include <hip/hip_runtime.h>

#define BB   16
#define C0   1024
#define C1   512
#define LEN  2048
#define BC   256
#define RC   64
#define NB0  4
#define NB1  2
#define KK   6
#define EPSV 1e-5f

// ---------------- Kernel 1: global-average-pool over blocks+L ----------------
// One block per (b, c). Sums 6 rows of 2048 floats, writes gap[b*BC+c] = sum/L.
__global__ __launch_bounds__(256) void gap_kernel(const float* __restrict__ x0,
                                                  const float* __restrict__ x1,
                                                  float* __restrict__ gap) {
    const int c = blockIdx.x;   // 0..255
    const int b = blockIdx.y;   // 0..15
    const int t = threadIdx.x;  // 0..255

    const float4* rows[KK];
#pragma unroll
    for (int k = 0; k < NB0; ++k)
        rows[k] = (const float4*)(x0 + ((size_t)b * C0 + (size_t)k * BC + c) * LEN);
#pragma unroll
    for (int k = 0; k < NB1; ++k)
        rows[NB0 + k] = (const float4*)(x1 + ((size_t)b * C1 + (size_t)k * BC + c) * LEN);

    float s = 0.f;
#pragma unroll
    for (int k = 0; k < KK; ++k) {
        float4 v0 = rows[k][t];
        float4 v1 = rows[k][t + 256];
        s += (v0.x + v0.y) + (v0.z + v0.w) + (v1.x + v1.y) + (v1.z + v1.w);
    }
    // wave(64) shuffle reduce
#pragma unroll
    for (int off = 32; off > 0; off >>= 1)
        s += __shfl_down(s, off, 64);
    __shared__ float ws_[4];
    if ((t & 63) == 0) ws_[t >> 6] = s;
    __syncthreads();
    if (t == 0) {
        float tot = (ws_[0] + ws_[1]) + (ws_[2] + ws_[3]);
        gap[b * BC + c] = tot * (1.0f / (float)LEN);
    }
}

// ------------- Kernel 2: joint linear + BN + ReLU, grouped linear, softmax ---
// One block per batch b. 256 threads; thread t handles channel c = t.
__global__ __launch_bounds__(256) void atten_kernel(const float* __restrict__ gap,
                                                    const float* __restrict__ Wj,   // [RC,BC]
                                                    const float* __restrict__ bj,   // [RC]
                                                    const float* __restrict__ gamma,
                                                    const float* __restrict__ beta,
                                                    const float* __restrict__ mean,
                                                    const float* __restrict__ var,
                                                    const float* __restrict__ Wg,   // [KK,BC,RC]
                                                    const float* __restrict__ bg,   // [KK,BC]
                                                    float* __restrict__ atten) {    // [KK,BB,BC]
    const int b = blockIdx.x;
    const int t = threadIdx.x;
    __shared__ float g_s[BC];
    __shared__ float h_s[RC];

    g_s[t] = gap[b * BC + t];
    __syncthreads();

    if (t < RC) {
        float acc = 0.f;
        const float* w = Wj + (size_t)t * BC;
        for (int c = 0; c < BC; ++c) acc = fmaf(g_s[c], w[c], acc);
        acc += bj[t];
        acc = (acc - mean[t]) * rsqrtf(var[t] + EPSV) * gamma[t] + beta[t];
        h_s[t] = fmaxf(acc, 0.f);
    }
    __syncthreads();

    float logit[KK];
#pragma unroll
    for (int k = 0; k < KK; ++k) {
        float acc = bg[k * BC + t];
        const float* w = Wg + ((size_t)k * BC + t) * RC;
#pragma unroll 8
        for (int r = 0; r < RC; ++r) acc = fmaf(h_s[r], w[r], acc);
        logit[k] = acc;
    }
    float m = logit[0];
#pragma unroll
    for (int k = 1; k < KK; ++k) m = fmaxf(m, logit[k]);
    float sum = 0.f;
#pragma unroll
    for (int k = 0; k < KK; ++k) { logit[k] = expf(logit[k] - m); sum += logit[k]; }
    const float inv = 1.f / sum;
#pragma unroll
    for (int k = 0; k < KK; ++k)
        atten[((size_t)k * BB + b) * BC + t] = logit[k] * inv;
}

// ---------------- Kernel 3: broadcast scale -> out0 | out1 -------------------
// One block per channel-row. 24576 blocks, 256 threads, 2 float4 per thread.
__global__ __launch_bounds__(256) void scale_kernel(const float* __restrict__ x0,
                                                    const float* __restrict__ x1,
                                                    const float* __restrict__ atten,
                                                    float* __restrict__ out) {
    const int row = blockIdx.x;            // 0..24575
    const int b  = row / (C0 + C1);        // /1536
    const int ch = row - b * (C0 + C1);
    const int t  = threadIdx.x;

    const float4* src;
    float4* dst;
    float scale;
    if (ch < C0) {
        const int k = ch >> 8, c = ch & 255;
        scale = atten[((size_t)k * BB + b) * BC + c];
        src = (const float4*)(x0 + ((size_t)b * C0 + ch) * LEN);
        dst = (float4*)(out + ((size_t)b * C0 + ch) * LEN);
    } else {
        const int ch1 = ch - C0;
        const int k = NB0 + (ch1 >> 8), c = ch1 & 255;
        scale = atten[((size_t)k * BB + b) * BC + c];
        src = (const float4*)(x1 + ((size_t)b * C1 + ch1) * LEN);
        dst = (float4*)(out + (size_t)BB * C0 * LEN + ((size_t)b * C1 + ch1) * LEN);
    }
    float4 v0 = src[t];
    float4 v1 = src[t + 256];
    v0.x *= scale; v0.y *= scale; v0.z *= scale; v0.w *= scale;
    v1.x *= scale; v1.y *= scale; v1.z *= scale; v1.w *= scale;
    dst[t] = v0;
    dst[t + 256] = v1;
}

extern "C" void kernel_launch(void* const* d_in, const int* in_sizes, int n_in,
                              void* d_out, int out_size, void* d_ws, size_t ws_size,
                              hipStream_t stream) {
    const float* x0    = (const float*)d_in[0];
    const float* x1    = (const float*)d_in[1];
    const float* Wj    = (const float*)d_in[2];
    const float* bj    = (const float*)d_in[3];
    const float* gamma = (const float*)d_in[4];
    const float* beta  = (const float*)d_in[5];
    const float* mean  = (const float*)d_in[6];
    const float* var   = (const float*)d_in[7];
    const float* Wg    = (const float*)d_in[8];
    const float* bg    = (const float*)d_in[9];
    float* out = (float*)d_out;

    float* ws    = (float*)d_ws;
    float* gap   = ws;          // BB*BC          = 4096 floats
    float* atten = ws + 4096;   // KK*BB*BC       = 24576 floats

    gap_kernel<<<dim3(BC, BB), 256, 0, stream>>>(x0, x1, gap);
    atten_kernel<<<BB, 256, 0, stream>>>(gap, Wj, bj, gamma, beta, mean, var, Wg, bg, atten);
    scale_kernel<<<BB * (C0 + C1), 256, 0, stream>>>(x0, x1, atten, out);
}

// Round 3
// 400.153 us; speedup vs baseline: 1.0062x; 1.0062x over previous
//
#include <hip/hip_runtime.h>

#define BB   16
#define C0   1024
#define C1   512
#define LEN  2048
#define BC   256
#define RC   64
#define NB0  4
#define NB1  2
#define KK   6
#define EPSV 1e-5f

// native clang vector type — works with __builtin_nontemporal_store
typedef float vfloat4 __attribute__((ext_vector_type(4)));

// ---------------- Kernel 1: global-average-pool over blocks+L ----------------
// One block per (b, c). Sums 6 rows of 2048 floats, writes gap[b*BC+c] = sum/L.
// Normal (caching) loads on purpose: this pass warms x into L3 for kernel 3.
__global__ __launch_bounds__(256) void gap_kernel(const float* __restrict__ x0,
                                                  const float* __restrict__ x1,
                                                  float* __restrict__ gap) {
    const int c = blockIdx.x;   // 0..255
    const int b = blockIdx.y;   // 0..15
    const int t = threadIdx.x;  // 0..255

    const vfloat4* rows[KK];
#pragma unroll
    for (int k = 0; k < NB0; ++k)
        rows[k] = (const vfloat4*)(x0 + ((size_t)b * C0 + (size_t)k * BC + c) * LEN);
#pragma unroll
    for (int k = 0; k < NB1; ++k)
        rows[NB0 + k] = (const vfloat4*)(x1 + ((size_t)b * C1 + (size_t)k * BC + c) * LEN);

    float s = 0.f;
#pragma unroll
    for (int k = 0; k < KK; ++k) {
        vfloat4 v0 = rows[k][t];
        vfloat4 v1 = rows[k][t + 256];
        s += (v0.x + v0.y) + (v0.z + v0.w) + (v1.x + v1.y) + (v1.z + v1.w);
    }
#pragma unroll
    for (int off = 32; off > 0; off >>= 1)
        s += __shfl_down(s, off, 64);
    __shared__ float ws_[4];
    if ((t & 63) == 0) ws_[t >> 6] = s;
    __syncthreads();
    if (t == 0) {
        float tot = (ws_[0] + ws_[1]) + (ws_[2] + ws_[3]);
        gap[b * BC + c] = tot * (1.0f / (float)LEN);
    }
}

// ------------- Kernel 2: joint linear + BN + ReLU, grouped linear, softmax ---
// One block per batch b. Wj GEMV done wave-parallel with coalesced 256B loads
// + shuffle reduce (all 256 threads active). Wg reads stay per-thread (L2-hot,
// 384 KB total, plenty of MLP from the unrolled r-loop).
__global__ __launch_bounds__(256) void atten_kernel(const float* __restrict__ gap,
                                                    const float* __restrict__ Wj,   // [RC,BC]
                                                    const float* __restrict__ bj,   // [RC]
                                                    const float* __restrict__ gamma,
                                                    const float* __restrict__ beta,
                                                    const float* __restrict__ mean,
                                                    const float* __restrict__ var,
                                                    const float* __restrict__ Wg,   // [KK,BC,RC]
                                                    const float* __restrict__ bg,   // [KK,BC]
                                                    float* __restrict__ atten) {    // [KK,BB,BC]
    const int b    = blockIdx.x;
    const int t    = threadIdx.x;
    const int lane = t & 63;
    const int wave = t >> 6;
    __shared__ float g_s[BC];
    __shared__ float h_s[RC];

    g_s[t] = gap[b * BC + t];
    __syncthreads();

    // h[r] for r = wave*16 .. wave*16+15 : coalesced Wj row loads + wave reduce
#pragma unroll
    for (int i = 0; i < 16; ++i) {
        const int r = wave * 16 + i;
        const float* w = Wj + (size_t)r * BC;
        float acc = fmaf(w[lane], g_s[lane],
                    fmaf(w[lane + 64], g_s[lane + 64],
                    fmaf(w[lane + 128], g_s[lane + 128],
                         w[lane + 192] * g_s[lane + 192])));
#pragma unroll
        for (int off = 32; off > 0; off >>= 1)
            acc += __shfl_down(acc, off, 64);
        if (lane == 0) {
            float v = acc + bj[r];
            v = (v - mean[r]) * rsqrtf(var[r] + EPSV) * gamma[r] + beta[r];
            h_s[r] = fmaxf(v, 0.f);
        }
    }
    __syncthreads();

    float logit[KK];
#pragma unroll
    for (int k = 0; k < KK; ++k) {
        float acc = bg[k * BC + t];
        const float* w = Wg + ((size_t)k * BC + t) * RC;
#pragma unroll
        for (int r = 0; r < RC; ++r) acc = fmaf(h_s[r], w[r], acc);
        logit[k] = acc;
    }
    float m = logit[0];
#pragma unroll
    for (int k = 1; k < KK; ++k) m = fmaxf(m, logit[k]);
    float sum = 0.f;
#pragma unroll
    for (int k = 0; k < KK; ++k) { logit[k] = __expf(logit[k] - m); sum += logit[k]; }
    const float inv = 1.f / sum;
#pragma unroll
    for (int k = 0; k < KK; ++k)
        atten[((size_t)k * BB + b) * BC + t] = logit[k] * inv;
}

// ---------------- Kernel 3: broadcast scale -> out0 | out1 -------------------
// One block per channel-row. x loads are normal (should hit L3, warmed by K1);
// out stores are NON-TEMPORAL so the 201MB output stream doesn't evict x.
__global__ __launch_bounds__(256) void scale_kernel(const float* __restrict__ x0,
                                                    const float* __restrict__ x1,
                                                    const float* __restrict__ atten,
                                                    float* __restrict__ out) {
    const int row = blockIdx.x;            // 0..24575
    const int b  = row / (C0 + C1);
    const int ch = row - b * (C0 + C1);
    const int t  = threadIdx.x;

    const vfloat4* src;
    vfloat4* dst;
    float scale;
    if (ch < C0) {
        const int k = ch >> 8, c = ch & 255;
        scale = atten[((size_t)k * BB + b) * BC + c];
        src = (const vfloat4*)(x0 + ((size_t)b * C0 + ch) * LEN);
        dst = (vfloat4*)(out + ((size_t)b * C0 + ch) * LEN);
    } else {
        const int ch1 = ch - C0;
        const int k = NB0 + (ch1 >> 8), c = ch1 & 255;
        scale = atten[((size_t)k * BB + b) * BC + c];
        src = (const vfloat4*)(x1 + ((size_t)b * C1 + ch1) * LEN);
        dst = (vfloat4*)(out + (size_t)BB * C0 * LEN + ((size_t)b * C1 + ch1) * LEN);
    }
    vfloat4 v0 = src[t];
    vfloat4 v1 = src[t + 256];
    v0 *= scale;
    v1 *= scale;
    __builtin_nontemporal_store(v0, &dst[t]);
    __builtin_nontemporal_store(v1, &dst[t + 256]);
}

extern "C" void kernel_launch(void* const* d_in, const int* in_sizes, int n_in,
                              void* d_out, int out_size, void* d_ws, size_t ws_size,
                              hipStream_t stream) {
    const float* x0    = (const float*)d_in[0];
    const float* x1    = (const float*)d_in[1];
    const float* Wj    = (const float*)d_in[2];
    const float* bj    = (const float*)d_in[3];
    const float* gamma = (const float*)d_in[4];
    const float* beta  = (const float*)d_in[5];
    const float* mean  = (const float*)d_in[6];
    const float* var   = (const float*)d_in[7];
    const float* Wg    = (const float*)d_in[8];
    const float* bg    = (const float*)d_in[9];
    float* out = (float*)d_out;

    float* ws    = (float*)d_ws;
    float* gap   = ws;          // BB*BC    = 4096 floats
    float* atten = ws + 4096;   // KK*BB*BC = 24576 floats

    gap_kernel<<<dim3(BC, BB), 256, 0, stream>>>(x0, x1, gap);
    atten_kernel<<<BB, 256, 0, stream>>>(gap, Wj, bj, gamma, beta, mean, var, Wg, bg, atten);
    scale_kernel<<<BB * (C0 + C1), 256, 0, stream>>>(x0, x1, atten, out);
}

// Round 4
// 390.410 us; speedup vs baseline: 1.0314x; 1.0250x over previous
//
#include <hip/hip_runtime.h>

#define BB   16
#define C0   1024
#define C1   512
#define LEN  2048
#define BC   256
#define RC   64
#define NB0  4
#define NB1  2
#define KK   6
#define EPSV 1e-5f

// native clang vector type — works with __builtin_nontemporal_store
typedef float vfloat4 __attribute__((ext_vector_type(4)));

// ---------------- Kernel 1: global-average-pool over blocks+L ----------------
// One block per (b, c). Sums 6 rows of 2048 floats, writes gap[b*BC+c] = sum/L.
// Normal (caching) loads on purpose: this pass warms x into L3 for kernel 3.
__global__ __launch_bounds__(256) void gap_kernel(const float* __restrict__ x0,
                                                  const float* __restrict__ x1,
                                                  float* __restrict__ gap) {
    const int c = blockIdx.x;   // 0..255
    const int b = blockIdx.y;   // 0..15
    const int t = threadIdx.x;  // 0..255

    const vfloat4* rows[KK];
#pragma unroll
    for (int k = 0; k < NB0; ++k)
        rows[k] = (const vfloat4*)(x0 + ((size_t)b * C0 + (size_t)k * BC + c) * LEN);
#pragma unroll
    for (int k = 0; k < NB1; ++k)
        rows[NB0 + k] = (const vfloat4*)(x1 + ((size_t)b * C1 + (size_t)k * BC + c) * LEN);

    float s = 0.f;
#pragma unroll
    for (int k = 0; k < KK; ++k) {
        vfloat4 v0 = rows[k][t];
        vfloat4 v1 = rows[k][t + 256];
        s += (v0.x + v0.y) + (v0.z + v0.w) + (v1.x + v1.y) + (v1.z + v1.w);
    }
#pragma unroll
    for (int off = 32; off > 0; off >>= 1)
        s += __shfl_down(s, off, 64);
    __shared__ float ws_[4];
    if ((t & 63) == 0) ws_[t >> 6] = s;
    __syncthreads();
    if (t == 0) {
        float tot = (ws_[0] + ws_[1]) + (ws_[2] + ws_[3]);
        gap[b * BC + c] = tot * (1.0f / (float)LEN);
    }
}

// ------------- Kernel 2: joint linear + BN + ReLU, grouped linear, softmax ---
// One block per batch b, 1024 threads (16 waves). The 16-block launch is
// latency-bound on cold Wg HBM reads; 1536 threads each loading a contiguous
// 256B Wg row gives ~6x the memory-level parallelism of the 256-thread
// version (which had each of 256 threads serially chasing 1.5KB).
__global__ __launch_bounds__(1024) void atten_kernel(const float* __restrict__ gap,
                                                     const float* __restrict__ Wj,   // [RC,BC]
                                                     const float* __restrict__ bj,   // [RC]
                                                     const float* __restrict__ gamma,
                                                     const float* __restrict__ beta,
                                                     const float* __restrict__ mean,
                                                     const float* __restrict__ var,
                                                     const float* __restrict__ Wg,   // [KK,BC,RC]
                                                     const float* __restrict__ bg,   // [KK,BC]
                                                     float* __restrict__ atten) {    // [KK,BB,BC]
    const int b    = blockIdx.x;
    const int t    = threadIdx.x;   // 0..1023
    const int lane = t & 63;
    const int wave = t >> 6;        // 0..15
    __shared__ float g_s[BC];
    __shared__ float h_s[RC];
    __shared__ float l_s[KK][BC];

    if (t < BC) g_s[t] = gap[b * BC + t];
    __syncthreads();

    // h[r] for r = wave*4 .. wave*4+3 : coalesced Wj row loads + wave reduce
#pragma unroll
    for (int i = 0; i < 4; ++i) {
        const int r = wave * 4 + i;
        const float* w = Wj + (size_t)r * BC;
        float acc = fmaf(w[lane], g_s[lane],
                    fmaf(w[lane + 64], g_s[lane + 64],
                    fmaf(w[lane + 128], g_s[lane + 128],
                         w[lane + 192] * g_s[lane + 192])));
#pragma unroll
        for (int off = 32; off > 0; off >>= 1)
            acc += __shfl_down(acc, off, 64);
        if (lane == 0) {
            float v = acc + bj[r];
            v = (v - mean[r]) * rsqrtf(var[r] + EPSV) * gamma[r] + beta[r];
            h_s[r] = fmaxf(v, 0.f);
        }
    }
    __syncthreads();

    // logits: 1536 (k,c) pairs over 1024 threads -> t and t+1024 slots
    if (t < KK * BC) {
        const int k = t >> 8, c = t & 255;
        float acc = bg[k * BC + c];
        const float* w = Wg + ((size_t)k * BC + c) * RC;
#pragma unroll
        for (int r = 0; r < RC; ++r) acc = fmaf(h_s[r], w[r], acc);
        l_s[k][c] = acc;
    }
    const int t2 = t + 1024;
    if (t2 < KK * BC) {
        const int k = t2 >> 8, c = t2 & 255;
        float acc = bg[k * BC + c];
        const float* w = Wg + ((size_t)k * BC + c) * RC;
#pragma unroll
        for (int r = 0; r < RC; ++r) acc = fmaf(h_s[r], w[r], acc);
        l_s[k][c] = acc;
    }
    __syncthreads();

    if (t < BC) {
        float logit[KK];
#pragma unroll
        for (int k = 0; k < KK; ++k) logit[k] = l_s[k][t];
        float m = logit[0];
#pragma unroll
        for (int k = 1; k < KK; ++k) m = fmaxf(m, logit[k]);
        float sum = 0.f;
#pragma unroll
        for (int k = 0; k < KK; ++k) { logit[k] = __expf(logit[k] - m); sum += logit[k]; }
        const float inv = 1.f / sum;
#pragma unroll
        for (int k = 0; k < KK; ++k)
            atten[((size_t)k * BB + b) * BC + t] = logit[k] * inv;
    }
}

// ---------------- Kernel 3: broadcast scale -> out0 | out1 -------------------
// One block per channel-row. x loads are normal (should hit L3, warmed by K1);
// out stores are NON-TEMPORAL so the 201MB output stream doesn't evict x.
__global__ __launch_bounds__(256) void scale_kernel(const float* __restrict__ x0,
                                                    const float* __restrict__ x1,
                                                    const float* __restrict__ atten,
                                                    float* __restrict__ out) {
    const int row = blockIdx.x;            // 0..24575
    const int b  = row / (C0 + C1);
    const int ch = row - b * (C0 + C1);
    const int t  = threadIdx.x;

    const vfloat4* src;
    vfloat4* dst;
    float scale;
    if (ch < C0) {
        const int k = ch >> 8, c = ch & 255;
        scale = atten[((size_t)k * BB + b) * BC + c];
        src = (const vfloat4*)(x0 + ((size_t)b * C0 + ch) * LEN);
        dst = (vfloat4*)(out + ((size_t)b * C0 + ch) * LEN);
    } else {
        const int ch1 = ch - C0;
        const int k = NB0 + (ch1 >> 8), c = ch1 & 255;
        scale = atten[((size_t)k * BB + b) * BC + c];
        src = (const vfloat4*)(x1 + ((size_t)b * C1 + ch1) * LEN);
        dst = (vfloat4*)(out + (size_t)BB * C0 * LEN + ((size_t)b * C1 + ch1) * LEN);
    }
    vfloat4 v0 = src[t];
    vfloat4 v1 = src[t + 256];
    v0 *= scale;
    v1 *= scale;
    __builtin_nontemporal_store(v0, &dst[t]);
    __builtin_nontemporal_store(v1, &dst[t + 256]);
}

extern "C" void kernel_launch(void* const* d_in, const int* in_sizes, int n_in,
                              void* d_out, int out_size, void* d_ws, size_t ws_size,
                              hipStream_t stream) {
    const float* x0    = (const float*)d_in[0];
    const float* x1    = (const float*)d_in[1];
    const float* Wj    = (const float*)d_in[2];
    const float* bj    = (const float*)d_in[3];
    const float* gamma = (const float*)d_in[4];
    const float* beta  = (const float*)d_in[5];
    const float* mean  = (const float*)d_in[6];
    const float* var   = (const float*)d_in[7];
    const float* Wg    = (const float*)d_in[8];
    const float* bg    = (const float*)d_in[9];
    float* out = (float*)d_out;

    float* ws    = (float*)d_ws;
    float* gap   = ws;          // BB*BC    = 4096 floats
    float* atten = ws + 4096;   // KK*BB*BC = 24576 floats

    gap_kernel<<<dim3(BC, BB), 256, 0, stream>>>(x0, x1, gap);
    atten_kernel<<<BB, 1024, 0, stream>>>(gap, Wj, bj, gamma, beta, mean, var, Wg, bg, atten);
    scale_kernel<<<BB * (C0 + C1), 256, 0, stream>>>(x0, x1, atten, out);
}